// Round 5
// baseline (346.699 us; speedup 1.0000x reference)
//
#include <hip/hip_runtime.h>
#include <stdint.h>

// Problem shape (fixed by setup_inputs)
#define BB 64
#define CC 128
#define HW 3136
#define NPR (CC * HW)        // 401408 per row
#define NF4 (NPR / 4)        // 100352
#define F4CH (HW / 4)        // 784 float4 per channel
#define SS 2048              // float4 samples per row (8192 floats)
#define SSTRIDE 49           // NF4 = SS * 49 exactly
#define MARGIN 400           // sample-rank margin (~14.7 sigma)

typedef float vf4 __attribute__((ext_vector_type(4)));

// ws layout: [0,256) Thi u32[64] | [256,512) Tlo | [512,768) chi | [768,1024) counters
//            [4096, ...) cand u64[64][cap]
#define THI_OFF 0
#define TLO_OFF 256
#define CHI_OFF 512
#define CNT_OFF 768
#define CAND_OFF 4096

__device__ __forceinline__ uint32_t tokey(float b) {
    uint32_t u = __float_as_uint(b);
    return u ^ (uint32_t)(((int32_t)u >> 31) | 0x80000000);
}

__device__ __forceinline__ float boostf(const float* dc, int c, int K) {
    float td = (float)((double)K / (double)NPR);   // jnp.float32(k/n)
    float d = td - dc[c];
    return (float)exp((double)d);
}

// exact m-th largest among 8 in-register keys per thread (block-wide), 4 radix passes
__device__ uint32_t select32(const uint32_t* kreg, uint32_t m,
                             uint32_t* hh, uint32_t* sufs, int* sh_d) {
    int tid = threadIdx.x;
    uint32_t prefix = 0, mask = 0, remaining = m;
    for (int shift = 24; shift >= 0; shift -= 8) {
        if (tid < 256) hh[tid] = 0;
        __syncthreads();
        #pragma unroll
        for (int i = 0; i < 8; i++) {
            uint32_t v = kreg[i];
            if ((v & mask) == prefix) atomicAdd(&hh[(v >> shift) & 255u], 1u);
        }
        __syncthreads();
        if (tid < 256) sufs[tid] = hh[tid];
        __syncthreads();
        for (int off = 1; off < 256; off <<= 1) {
            uint32_t add = 0;
            if (tid < 256 && tid + off < 256) add = sufs[tid + off];
            __syncthreads();
            if (tid < 256) sufs[tid] += add;
            __syncthreads();
        }
        if (tid < 256) {
            uint32_t sd = sufs[tid], sn = (tid < 255) ? sufs[tid + 1] : 0u;
            if (sd >= remaining && sn < remaining) *sh_d = tid;
        }
        __syncthreads();
        int d = *sh_d;
        uint32_t cumG = (d < 255) ? sufs[d + 1] : 0u;
        prefix |= ((uint32_t)d << shift);
        mask |= (0xFFu << shift);
        remaining -= cumG;
        __syncthreads();
    }
    return prefix;
}

// exact E-th largest u64 among cnt candidates in cp (1<=E<=cnt); block-wide
__device__ unsigned long long select64(const unsigned long long* cp, uint32_t cnt,
                                       uint32_t E, uint32_t* hh, uint32_t* sufs,
                                       unsigned long long* lbuf, uint32_t* scnt,
                                       int* sh_d, int* sh_done) {
    int tid = threadIdx.x, nt = blockDim.x;
    unsigned long long prefix = 0ull, mask = 0ull, thr = 0ull;
    uint32_t remaining = E, csize = cnt;
    bool compacted = false;
    if (tid == 0) *sh_done = 0;
    __syncthreads();
    for (int shift = 56; shift >= 0; shift -= 8) {
        if (tid < 256) hh[tid] = 0;
        __syncthreads();
        if (!compacted) {
            for (uint32_t s = tid; s < cnt; s += nt) {
                unsigned long long v = cp[s];
                if ((v & mask) == prefix)
                    atomicAdd(&hh[(uint32_t)(v >> shift) & 255u], 1u);
            }
        } else {
            for (uint32_t s = tid; s < csize; s += nt)
                atomicAdd(&hh[(uint32_t)(lbuf[s] >> shift) & 255u], 1u);
        }
        __syncthreads();
        if (tid < 256) sufs[tid] = hh[tid];
        __syncthreads();
        for (int off = 1; off < 256; off <<= 1) {
            uint32_t add = 0;
            if (tid < 256 && tid + off < 256) add = sufs[tid + off];
            __syncthreads();
            if (tid < 256) sufs[tid] += add;
            __syncthreads();
        }
        if (tid < 256) {
            uint32_t sd = sufs[tid], sn = (tid < 255) ? sufs[tid + 1] : 0u;
            if (sd >= remaining && sn < remaining) *sh_d = tid;
        }
        __syncthreads();
        int d = *sh_d;
        uint32_t cumG = (d < 255) ? sufs[d + 1] : 0u;
        uint32_t binC = sufs[d] - cumG;
        unsigned long long npref = prefix | ((unsigned long long)(uint32_t)d << shift);
        bool done_ = (sufs[d] == remaining);
        if (done_) { thr = npref; if (tid == 0) *sh_done = 1; }
        remaining -= cumG;
        __syncthreads();
        if (!*sh_done && binC <= 4096u && shift > 0) {
            if (tid == 0) *scnt = 0;
            unsigned long long keep[8]; int nk = 0;
            if (compacted) {
                for (uint32_t s = tid; s < csize; s += nt) {
                    unsigned long long v = lbuf[s];
                    if (((uint32_t)(v >> shift) & 255u) == (uint32_t)d && nk < 8)
                        keep[nk++] = v;
                }
            }
            __syncthreads();
            if (!compacted) {
                for (uint32_t s = tid; s < cnt; s += nt) {
                    unsigned long long v = cp[s];
                    if ((v & mask) == prefix &&
                        ((uint32_t)(v >> shift) & 255u) == (uint32_t)d)
                        lbuf[atomicAdd(scnt, 1u)] = v;
                }
            } else if (nk > 0) {
                uint32_t p = atomicAdd(scnt, (uint32_t)nk);
                for (int i = 0; i < nk; i++) lbuf[p + i] = keep[i];
            }
            __syncthreads();
            csize = binC;
            compacted = true;
        }
        prefix = npref;
        mask |= (0xFFull << shift);
        if (*sh_done) break;
    }
    __syncthreads();
    if (!*sh_done) thr = prefix;
    return thr;
}

// ---- kernel 1: sample 8192 elements/row, exact-select bracket thresholds ----
__global__ __launch_bounds__(1024) void k_sample(const float* __restrict__ x,
                                                 const float* __restrict__ dc,
                                                 const int* __restrict__ kptr,
                                                 uint32_t* __restrict__ thi,
                                                 uint32_t* __restrict__ tlo) {
    __shared__ float sbf[CC];
    __shared__ uint32_t hh[256], sufs[256];
    __shared__ int sh_d;
    int row = blockIdx.x, tid = threadIdx.x;
    int K = *kptr;
    if (tid < CC) sbf[tid] = boostf(dc, tid, K);
    __syncthreads();
    const float4* xp = (const float4*)(x + (size_t)row * NPR);
    uint32_t kreg[8];
    #pragma unroll
    for (int h = 0; h < 2; h++) {
        int u = tid + h * 1024;                    // f4-sample index in [0, 2048)
        float4 v = xp[(size_t)u * SSTRIDE];
        float f = sbf[u >> 4];                     // 16 f4-samples per channel
        kreg[4*h+0] = tokey(v.x * f); kreg[4*h+1] = tokey(v.y * f);
        kreg[4*h+2] = tokey(v.z * f); kreg[4*h+3] = tokey(v.w * f);
    }
    int S = SS * 4;                                // 8192
    int m_mid = (int)(((long long)K * S) / NPR);
    int m_hi = m_mid - MARGIN; if (m_hi < 1) m_hi = 1;
    int m_lo = m_mid + MARGIN; if (m_lo > S) m_lo = S;
    uint32_t t1 = select32(kreg, (uint32_t)m_hi, hh, sufs, &sh_d);
    __syncthreads();
    uint32_t t2 = select32(kreg, (uint32_t)m_lo, hh, sufs, &sh_d);
    if (tid == 0) { thi[row] = t1; tlo[row] = t2; }
}

// wave-aggregated LDS append of a candidate
__device__ __forceinline__ void push_cand(bool isc, unsigned long long packed,
                                          uint32_t* lcnt, unsigned long long* lbuf,
                                          uint32_t* counters, unsigned long long* cand,
                                          int row, int cap) {
    unsigned long long ball = __ballot(isc);
    uint32_t tot = (uint32_t)__popcll(ball);
    if (tot == 0) return;
    uint32_t lo = (uint32_t)ball, hi = (uint32_t)(ball >> 32);
    uint32_t lanepre = __builtin_amdgcn_mbcnt_hi(hi, __builtin_amdgcn_mbcnt_lo(lo, 0));
    int leader = __ffsll((unsigned long long)ball) - 1;
    uint32_t base = 0;
    if (isc && lanepre == 0) base = atomicAdd(lcnt, tot);
    base = __shfl(base, leader, 64);
    if (isc) {
        uint32_t pos = base + lanepre;
        if (pos < 4096u) lbuf[pos] = packed;
        else {
            uint32_t gp = atomicAdd(&counters[row], 1u);
            if ((int)gp < cap) cand[(size_t)row * cap + gp] = packed;
        }
    }
}

// ---- kernel 2: stream out=x*(key>Thi), count sure-winners, compact bracket ----
__global__ __launch_bounds__(256) void k_stream(const float* __restrict__ x,
                                                const float* __restrict__ dc,
                                                const int* __restrict__ kptr,
                                                const uint32_t* __restrict__ thi,
                                                const uint32_t* __restrict__ tlo,
                                                float* __restrict__ out,
                                                unsigned long long* __restrict__ cand,
                                                uint32_t* __restrict__ counters,
                                                uint32_t* __restrict__ chi,
                                                int cap) {
    int row = blockIdx.x >> 4;                     // 64 rows x 16 groups of 8 channels
    int c0 = (blockIdx.x & 15) * 8;
    uint32_t Thi = thi[row], Tlo = tlo[row];

    __shared__ float sbf[8];
    __shared__ uint32_t lcnt, gbase;
    __shared__ unsigned long long lbuf[4096];      // 32 KiB
    __shared__ uint32_t red[256];
    if (threadIdx.x == 0) lcnt = 0;
    if (threadIdx.x < 8) sbf[threadIdx.x] = boostf(dc, c0 + threadIdx.x, *kptr);
    __syncthreads();

    size_t base = (size_t)row * NPR + (size_t)c0 * HW;
    const float4* xp = (const float4*)(x + base);
    vf4* op = (vf4*)(out + base);
    int jbase = c0 * HW;
    const int nf4 = 8 * HW / 4;                    // 6272
    uint32_t myhi = 0;

    int t = threadIdx.x;
    for (; t + 256 < nf4; t += 512) {
        float4 a = xp[t];
        float4 b = xp[t + 256];
        float fa = sbf[t / F4CH];
        float fb = sbf[(t + 256) / F4CH];
        vf4 oa, ob;
        float* ai = (float*)&a;
        float* bi = (float*)&b;
        #pragma unroll
        for (int q = 0; q < 4; q++) {
            float xv = ai[q];
            uint32_t key = tokey(xv * fa);
            bool win = key > Thi;
            myhi += win;
            oa[q] = win ? xv : 0.0f;
            bool isc = (!win) && (key > Tlo);
            uint32_t j = (uint32_t)(jbase + 4 * t + q);
            unsigned long long packed = ((unsigned long long)key << 32) | (uint32_t)(~j);
            push_cand(isc, packed, &lcnt, lbuf, counters, cand, row, cap);
        }
        #pragma unroll
        for (int q = 0; q < 4; q++) {
            float xv = bi[q];
            uint32_t key = tokey(xv * fb);
            bool win = key > Thi;
            myhi += win;
            ob[q] = win ? xv : 0.0f;
            bool isc = (!win) && (key > Tlo);
            uint32_t j = (uint32_t)(jbase + 4 * (t + 256) + q);
            unsigned long long packed = ((unsigned long long)key << 32) | (uint32_t)(~j);
            push_cand(isc, packed, &lcnt, lbuf, counters, cand, row, cap);
        }
        __builtin_nontemporal_store(oa, &op[t]);
        __builtin_nontemporal_store(ob, &op[t + 256]);
    }
    if (t < nf4) {                                 // tail: tid<128, whole waves active
        float4 a = xp[t];
        float fa = sbf[t / F4CH];
        vf4 oa;
        float* ai = (float*)&a;
        #pragma unroll
        for (int q = 0; q < 4; q++) {
            float xv = ai[q];
            uint32_t key = tokey(xv * fa);
            bool win = key > Thi;
            myhi += win;
            oa[q] = win ? xv : 0.0f;
            bool isc = (!win) && (key > Tlo);
            uint32_t j = (uint32_t)(jbase + 4 * t + q);
            unsigned long long packed = ((unsigned long long)key << 32) | (uint32_t)(~j);
            push_cand(isc, packed, &lcnt, lbuf, counters, cand, row, cap);
        }
        __builtin_nontemporal_store(oa, &op[t]);
    }
    __syncthreads();
    uint32_t m = lcnt < 4096u ? lcnt : 4096u;
    if (threadIdx.x == 0) gbase = atomicAdd(&counters[row], m);
    __syncthreads();
    for (uint32_t i = threadIdx.x; i < m; i += 256) {
        uint32_t pos = gbase + i;
        if ((int)pos < cap) cand[(size_t)row * cap + pos] = lbuf[i];
    }
    red[threadIdx.x] = myhi;
    __syncthreads();
    for (int off = 128; off > 0; off >>= 1) {
        if ((int)threadIdx.x < off) red[threadIdx.x] += red[threadIdx.x + off];
        __syncthreads();
    }
    if (threadIdx.x == 0) atomicAdd(&chi[row], red[0]);
}

// ---- kernel 3: exact select among candidates + scatter (fallback if miss) ----
__global__ __launch_bounds__(1024) void k_final(const float* __restrict__ x,
                                                const float* __restrict__ dc,
                                                const int* __restrict__ kptr,
                                                float* __restrict__ out,
                                                unsigned long long* __restrict__ cand,
                                                const uint32_t* __restrict__ counters,
                                                const uint32_t* __restrict__ chi,
                                                int cap) {
    __shared__ uint32_t hh[256], sufs[256];
    __shared__ unsigned long long lbuf[4096];      // aliased as 8192-bin hist in fallback
    __shared__ uint32_t cs1024[1024];
    __shared__ float sbf[CC];
    __shared__ uint32_t scnt;
    __shared__ int sh_d, sh_done, sh_b, sh_E;
    int row = blockIdx.x, tid = threadIdx.x;
    int K = *kptr;
    uint32_t cnt = counters[row], c_hi = chi[row];
    long long E = (long long)K - (long long)c_hi;
    unsigned long long* cp = cand + (size_t)row * cap;
    const float* xr = x + (size_t)row * NPR;
    float* orow = out + (size_t)row * NPR;

    bool ok = (E >= 0) && (E <= (long long)cnt) && ((int)cnt <= cap);
    if (ok) {
        if (E == 0) return;
        unsigned long long thr = select64(cp, cnt, (uint32_t)E, hh, sufs,
                                          lbuf, &scnt, &sh_d, &sh_done);
        for (uint32_t s = tid; s < cnt; s += 1024) {
            unsigned long long v = cp[s];
            if (v >= thr) { uint32_t j = ~(uint32_t)v; orow[j] = xr[j]; }
        }
        return;
    }

    // ------- fallback: exact full-row recompute (prob ~0, correctness net) ----
    uint32_t* lh = (uint32_t*)lbuf;                // 8192 bins (32 KiB)
    if (tid < CC) sbf[tid] = boostf(dc, tid, K);
    for (int i = tid; i < 8192; i += 1024) lh[i] = 0;
    __syncthreads();
    const float4* xp = (const float4*)xr;
    for (int t = tid; t < NF4; t += 1024) {
        float4 v = xp[t];
        float f = sbf[t / F4CH];
        atomicAdd(&lh[tokey(v.x * f) >> 19], 1u);
        atomicAdd(&lh[tokey(v.y * f) >> 19], 1u);
        atomicAdd(&lh[tokey(v.z * f) >> 19], 1u);
        atomicAdd(&lh[tokey(v.w * f) >> 19], 1u);
    }
    __syncthreads();
    {   // descending scan over 8192 bins (8 per thread)
        int hi = 8191 - 8 * tid;
        uint32_t s = 0;
        for (int j = 0; j < 8; j++) s += lh[hi - j];
        cs1024[tid] = s;
        __syncthreads();
        for (int off = 1; off < 1024; off <<= 1) {
            uint32_t v = (tid >= off) ? cs1024[tid - off] : 0u;
            __syncthreads();
            cs1024[tid] += v;
            __syncthreads();
        }
        uint32_t incl = cs1024[tid], excl = incl - s;
        if (excl < (uint32_t)K && incl >= (uint32_t)K) {
            uint32_t cum = excl;
            for (int j = 0; j < 8; j++) {
                int b = hi - j;
                uint32_t h = lh[b];
                if (cum + h >= (uint32_t)K) { sh_b = b; sh_E = (int)((uint32_t)K - cum); break; }
                cum += h;
            }
        }
    }
    __syncthreads();
    int bstar = sh_b;
    uint32_t E2 = (uint32_t)sh_E;
    if (tid == 0) scnt = 0;
    __syncthreads();
    for (int t = tid; t < NF4; t += 1024) {        // rewrite out + compact boundary bin
        float4 v = xp[t];
        float f = sbf[t / F4CH];
        vf4 o;
        float* vi = (float*)&v;
        #pragma unroll
        for (int q = 0; q < 4; q++) {
            float xv = vi[q];
            uint32_t key = tokey(xv * f);
            int bin = (int)(key >> 19);
            o[q] = (bin > bstar) ? xv : 0.0f;
            if (bin == bstar) {
                uint32_t j = (uint32_t)(4 * t + q);
                unsigned long long packed = ((unsigned long long)key << 32) | (uint32_t)(~j);
                uint32_t p = atomicAdd(&scnt, 1u);
                if ((int)p < cap) cp[p] = packed;
            }
        }
        ((vf4*)orow)[t] = o;
    }
    __syncthreads();
    uint32_t cnt2 = scnt;
    if ((int)cnt2 > cap) cnt2 = (uint32_t)cap;
    unsigned long long thr = select64(cp, cnt2, E2, hh, sufs, lbuf, &scnt, &sh_d, &sh_done);
    for (uint32_t s = tid; s < cnt2; s += 1024) {
        unsigned long long v = cp[s];
        if (v >= thr) { uint32_t j = ~(uint32_t)v; orow[j] = xr[j]; }
    }
}

extern "C" void kernel_launch(void* const* d_in, const int* in_sizes, int n_in,
                              void* d_out, int out_size, void* d_ws, size_t ws_size,
                              hipStream_t stream) {
    const float* x  = (const float*)d_in[0];
    const float* dc = (const float*)d_in[1];
    const int* kptr = (const int*)d_in[2];
    float* out = (float*)d_out;

    char* ws = (char*)d_ws;
    uint32_t* thi      = (uint32_t*)(ws + THI_OFF);
    uint32_t* tlo      = (uint32_t*)(ws + TLO_OFF);
    uint32_t* chi      = (uint32_t*)(ws + CHI_OFF);
    uint32_t* counters = (uint32_t*)(ws + CNT_OFF);
    unsigned long long* cand = (unsigned long long*)(ws + CAND_OFF);

    size_t cap_sz = (ws_size > CAND_OFF) ? (ws_size - CAND_OFF) / ((size_t)BB * 8) : 0;
    if (cap_sz > 65536) cap_sz = 65536;
    int cap = (int)cap_sz;

    (void)hipMemsetAsync(ws, 0, 4096, stream);     // zero thresholds/counters only
    k_sample<<<BB, 1024, 0, stream>>>(x, dc, kptr, thi, tlo);
    k_stream<<<BB * 16, 256, 0, stream>>>(x, dc, kptr, thi, tlo, out, cand, counters, chi, cap);
    k_final<<<BB, 1024, 0, stream>>>(x, dc, kptr, out, cand, counters, chi, cap);
}

// Round 6
// 277.123 us; speedup vs baseline: 1.2511x; 1.2511x over previous
//
#include <hip/hip_runtime.h>
#include <stdint.h>

// Problem shape (fixed by setup_inputs)
#define BB 64
#define CC 128
#define HW 3136
#define NPR (CC * HW)        // 401408 per row
#define NF4 (NPR / 4)        // 100352
#define F4CH (HW / 4)        // 784 float4 per channel
#define SS 2048              // float4 samples per row (8192 floats)
#define SSTRIDE 49           // NF4 = SS * 49 exactly
#define MARGIN 128           // sample-rank margin (~4.7 sigma; exact fallback guards)

typedef float vf4 __attribute__((ext_vector_type(4)));

// ws layout: [0,256) Thi u32[64] | [256,512) Tlo | [512,768) chi | [768,1024) counters
//            [4096, ...) cand u64[64][cap]  (packed key<<32 | ~idx)
#define THI_OFF 0
#define TLO_OFF 256
#define CHI_OFF 512
#define CNT_OFF 768
#define CAND_OFF 4096

__device__ __forceinline__ uint32_t tokey(float b) {
    uint32_t u = __float_as_uint(b);
    return u ^ (uint32_t)(((int32_t)u >> 31) | 0x80000000);
}
__device__ __forceinline__ float fromkey(uint32_t k) {
    uint32_t u = (k & 0x80000000u) ? (k ^ 0x80000000u) : ~k;
    return __uint_as_float(u);
}

__device__ __forceinline__ float boostf(const float* dc, int c, int K) {
    float td = (float)((double)K / (double)NPR);   // jnp.float32(k/n)
    float d = td - dc[c];
    return (float)exp((double)d);
}

// exact m-th largest among 8 in-register keys per thread (1024-thr block)
// per-wave privatized histograms: normal-dist keys concentrate in ~12 top-byte
// bins -> same-address LDS atomics serialize; 16-way wave privatization cuts it
__device__ uint32_t select32(const uint32_t* kreg, uint32_t m,
                             uint32_t* whist /*16*256*/, uint32_t* sufs, int* sh_d) {
    int tid = threadIdx.x;
    int wid = tid >> 6;
    uint32_t prefix = 0, mask = 0, remaining = m;
    for (int shift = 24; shift >= 0; shift -= 8) {
        for (int i = tid; i < 16 * 256; i += 1024) whist[i] = 0;
        __syncthreads();
        #pragma unroll
        for (int i = 0; i < 8; i++) {
            uint32_t v = kreg[i];
            if ((v & mask) == prefix)
                atomicAdd(&whist[(wid << 8) + ((v >> shift) & 255u)], 1u);
        }
        __syncthreads();
        if (tid < 256) {
            uint32_t s = 0;
            for (int w = 0; w < 16; w++) s += whist[(w << 8) + tid];
            sufs[tid] = s;
        }
        __syncthreads();
        for (int off = 1; off < 256; off <<= 1) {  // suffix sums (descending)
            uint32_t add = 0;
            if (tid < 256 && tid + off < 256) add = sufs[tid + off];
            __syncthreads();
            if (tid < 256) sufs[tid] += add;
            __syncthreads();
        }
        if (tid < 256) {
            uint32_t sd = sufs[tid], sn = (tid < 255) ? sufs[tid + 1] : 0u;
            if (sd >= remaining && sn < remaining) *sh_d = tid;
        }
        __syncthreads();
        int d = *sh_d;
        uint32_t cumG = (d < 255) ? sufs[d + 1] : 0u;
        prefix |= ((uint32_t)d << shift);
        mask |= (0xFFu << shift);
        remaining -= cumG;
        __syncthreads();
    }
    return prefix;
}

// exact E-th largest u64 among cnt candidates (rare path / fallback only)
__device__ unsigned long long select64(const unsigned long long* cp, uint32_t cnt,
                                       uint32_t E, uint32_t* hh, uint32_t* sufs,
                                       unsigned long long* lbuf, uint32_t* scnt,
                                       int* sh_d, int* sh_done) {
    int tid = threadIdx.x, nt = blockDim.x;
    unsigned long long prefix = 0ull, mask = 0ull, thr = 0ull;
    uint32_t remaining = E, csize = cnt;
    bool compacted = false;
    if (tid == 0) *sh_done = 0;
    __syncthreads();
    for (int shift = 56; shift >= 0; shift -= 8) {
        if (tid < 256) hh[tid] = 0;
        __syncthreads();
        if (!compacted) {
            for (uint32_t s = tid; s < cnt; s += nt) {
                unsigned long long v = cp[s];
                if ((v & mask) == prefix)
                    atomicAdd(&hh[(uint32_t)(v >> shift) & 255u], 1u);
            }
        } else {
            for (uint32_t s = tid; s < csize; s += nt)
                atomicAdd(&hh[(uint32_t)(lbuf[s] >> shift) & 255u], 1u);
        }
        __syncthreads();
        if (tid < 256) sufs[tid] = hh[tid];
        __syncthreads();
        for (int off = 1; off < 256; off <<= 1) {
            uint32_t add = 0;
            if (tid < 256 && tid + off < 256) add = sufs[tid + off];
            __syncthreads();
            if (tid < 256) sufs[tid] += add;
            __syncthreads();
        }
        if (tid < 256) {
            uint32_t sd = sufs[tid], sn = (tid < 255) ? sufs[tid + 1] : 0u;
            if (sd >= remaining && sn < remaining) *sh_d = tid;
        }
        __syncthreads();
        int d = *sh_d;
        uint32_t cumG = (d < 255) ? sufs[d + 1] : 0u;
        uint32_t binC = sufs[d] - cumG;
        unsigned long long npref = prefix | ((unsigned long long)(uint32_t)d << shift);
        bool done_ = (sufs[d] == remaining);
        if (done_) { thr = npref; if (tid == 0) *sh_done = 1; }
        remaining -= cumG;
        __syncthreads();
        if (!*sh_done && binC <= 4096u && shift > 0) {
            if (tid == 0) *scnt = 0;
            unsigned long long keep[8]; int nk = 0;
            if (compacted) {
                for (uint32_t s = tid; s < csize; s += nt) {
                    unsigned long long v = lbuf[s];
                    if (((uint32_t)(v >> shift) & 255u) == (uint32_t)d && nk < 8)
                        keep[nk++] = v;
                }
            }
            __syncthreads();
            if (!compacted) {
                for (uint32_t s = tid; s < cnt; s += nt) {
                    unsigned long long v = cp[s];
                    if ((v & mask) == prefix &&
                        ((uint32_t)(v >> shift) & 255u) == (uint32_t)d)
                        lbuf[atomicAdd(scnt, 1u)] = v;
                }
            } else if (nk > 0) {
                uint32_t p = atomicAdd(scnt, (uint32_t)nk);
                for (int i = 0; i < nk; i++) lbuf[p + i] = keep[i];
            }
            __syncthreads();
            csize = binC;
            compacted = true;
        }
        prefix = npref;
        mask |= (0xFFull << shift);
        if (*sh_done) break;
    }
    __syncthreads();
    if (!*sh_done) thr = prefix;
    return thr;
}

// ---- kernel 1: sample 8192 elements/row, exact-select bracket thresholds ----
__global__ __launch_bounds__(1024) void k_sample(const float* __restrict__ x,
                                                 const float* __restrict__ dc,
                                                 const int* __restrict__ kptr,
                                                 uint32_t* __restrict__ thi,
                                                 uint32_t* __restrict__ tlo) {
    __shared__ float sbf[CC];
    __shared__ uint32_t whist[16 * 256];           // 16 KiB
    __shared__ uint32_t sufs[256];
    __shared__ int sh_d;
    int row = blockIdx.x, tid = threadIdx.x;
    int K = *kptr;
    if (tid < CC) sbf[tid] = boostf(dc, tid, K);
    __syncthreads();
    const float4* xp = (const float4*)(x + (size_t)row * NPR);
    uint32_t kreg[8];
    #pragma unroll
    for (int h = 0; h < 2; h++) {
        int u = tid + h * 1024;                    // f4-sample index in [0, 2048)
        float4 v = xp[(size_t)u * SSTRIDE];
        float f = sbf[u >> 4];                     // 16 f4-samples per channel
        kreg[4*h+0] = tokey(v.x * f); kreg[4*h+1] = tokey(v.y * f);
        kreg[4*h+2] = tokey(v.z * f); kreg[4*h+3] = tokey(v.w * f);
    }
    int S = SS * 4;                                // 8192
    int m_mid = (int)(((long long)K * S) / NPR);
    int m_hi = m_mid - MARGIN; if (m_hi < 1) m_hi = 1;
    int m_lo = m_mid + MARGIN; if (m_lo > S) m_lo = S;
    uint32_t t1 = select32(kreg, (uint32_t)m_hi, whist, sufs, &sh_d);
    __syncthreads();
    uint32_t t2 = select32(kreg, (uint32_t)m_lo, whist, sufs, &sh_d);
    if (tid == 0) { thi[row] = t1; tlo[row] = t2; }
}

// wave-aggregated LDS append of a candidate
__device__ __forceinline__ void push_cand(bool isc, unsigned long long packed,
                                          uint32_t* lcnt, unsigned long long* lbuf,
                                          uint32_t* counters, unsigned long long* cand,
                                          int row, int cap) {
    unsigned long long ball = __ballot(isc);
    uint32_t tot = (uint32_t)__popcll(ball);
    if (tot == 0) return;
    uint32_t lo = (uint32_t)ball, hi = (uint32_t)(ball >> 32);
    uint32_t lanepre = __builtin_amdgcn_mbcnt_hi(hi, __builtin_amdgcn_mbcnt_lo(lo, 0));
    int leader = __ffsll((unsigned long long)ball) - 1;
    uint32_t base = 0;
    if (isc && lanepre == 0) base = atomicAdd(lcnt, tot);
    base = __shfl(base, leader, 64);
    if (isc) {
        uint32_t pos = base + lanepre;
        if (pos < 4096u) lbuf[pos] = packed;
        else {
            uint32_t gp = atomicAdd(&counters[row], 1u);
            if ((int)gp < cap) cand[(size_t)row * cap + gp] = packed;
        }
    }
}

// ---- kernel 2: stream out=x*(b>Bhi), count sure-winners, compact bracket ----
__global__ __launch_bounds__(256) void k_stream(const float* __restrict__ x,
                                                const float* __restrict__ dc,
                                                const int* __restrict__ kptr,
                                                const uint32_t* __restrict__ thi,
                                                const uint32_t* __restrict__ tlo,
                                                float* __restrict__ out,
                                                unsigned long long* __restrict__ cand,
                                                uint32_t* __restrict__ counters,
                                                uint32_t* __restrict__ chi,
                                                int cap) {
    int row = blockIdx.x >> 4;                     // 64 rows x 16 groups of 8 channels
    int c0 = (blockIdx.x & 15) * 8;
    float Bhi = fromkey(thi[row]);                 // float-domain compares (fewer VALU)
    float Blo = fromkey(tlo[row]);

    __shared__ float sbf[8];
    __shared__ uint32_t lcnt, gbase;
    __shared__ unsigned long long lbuf[4096];      // 32 KiB
    __shared__ uint32_t red[256];
    if (threadIdx.x == 0) lcnt = 0;
    if (threadIdx.x < 8) sbf[threadIdx.x] = boostf(dc, c0 + threadIdx.x, *kptr);
    __syncthreads();

    size_t base = (size_t)row * NPR + (size_t)c0 * HW;
    const float4* xp = (const float4*)(x + base);
    vf4* op = (vf4*)(out + base);
    int jbase = c0 * HW;
    const int nf4 = 8 * HW / 4;                    // 6272
    uint32_t myhi = 0;

    int t = threadIdx.x;
    for (; t + 256 < nf4; t += 512) {
        float4 a = xp[t];
        float4 b = xp[t + 256];
        float fa = sbf[t / F4CH];
        float fb = sbf[(t + 256) / F4CH];
        vf4 oa, ob;
        float* ai = (float*)&a;
        float* bi = (float*)&b;
        #pragma unroll
        for (int q = 0; q < 4; q++) {
            float xv = ai[q];
            float bv = xv * fa;
            bool win = bv > Bhi;
            myhi += win;
            oa[q] = win ? xv : 0.0f;
            bool isc = (bv > Blo) && !win;
            uint32_t j = (uint32_t)(jbase + 4 * t + q);
            unsigned long long packed = ((unsigned long long)tokey(bv) << 32) | (uint32_t)(~j);
            push_cand(isc, packed, &lcnt, lbuf, counters, cand, row, cap);
        }
        #pragma unroll
        for (int q = 0; q < 4; q++) {
            float xv = bi[q];
            float bv = xv * fb;
            bool win = bv > Bhi;
            myhi += win;
            ob[q] = win ? xv : 0.0f;
            bool isc = (bv > Blo) && !win;
            uint32_t j = (uint32_t)(jbase + 4 * (t + 256) + q);
            unsigned long long packed = ((unsigned long long)tokey(bv) << 32) | (uint32_t)(~j);
            push_cand(isc, packed, &lcnt, lbuf, counters, cand, row, cap);
        }
        __builtin_nontemporal_store(oa, &op[t]);
        __builtin_nontemporal_store(ob, &op[t + 256]);
    }
    if (t < nf4) {                                 // tail: tid<128, whole waves active
        float4 a = xp[t];
        float fa = sbf[t / F4CH];
        vf4 oa;
        float* ai = (float*)&a;
        #pragma unroll
        for (int q = 0; q < 4; q++) {
            float xv = ai[q];
            float bv = xv * fa;
            bool win = bv > Bhi;
            myhi += win;
            oa[q] = win ? xv : 0.0f;
            bool isc = (bv > Blo) && !win;
            uint32_t j = (uint32_t)(jbase + 4 * t + q);
            unsigned long long packed = ((unsigned long long)tokey(bv) << 32) | (uint32_t)(~j);
            push_cand(isc, packed, &lcnt, lbuf, counters, cand, row, cap);
        }
        __builtin_nontemporal_store(oa, &op[t]);
    }
    __syncthreads();
    uint32_t m = lcnt < 4096u ? lcnt : 4096u;
    if (threadIdx.x == 0) gbase = atomicAdd(&counters[row], m);
    __syncthreads();
    for (uint32_t i = threadIdx.x; i < m; i += 256) {
        uint32_t pos = gbase + i;
        if ((int)pos < cap) cand[(size_t)row * cap + pos] = lbuf[i];
    }
    red[threadIdx.x] = myhi;
    __syncthreads();
    for (int off = 128; off > 0; off >>= 1) {
        if ((int)threadIdx.x < off) red[threadIdx.x] += red[threadIdx.x + off];
        __syncthreads();
    }
    if (threadIdx.x == 0) atomicAdd(&chi[row], red[0]);
}

// ---- kernel 3: interpolation-select exact E-th among candidates + scatter ----
__global__ __launch_bounds__(1024) void k_final(const float* __restrict__ x,
                                                const float* __restrict__ dc,
                                                const int* __restrict__ kptr,
                                                const uint32_t* __restrict__ thi,
                                                const uint32_t* __restrict__ tlo,
                                                float* __restrict__ out,
                                                unsigned long long* __restrict__ cand,
                                                const uint32_t* __restrict__ counters,
                                                const uint32_t* __restrict__ chi,
                                                int cap) {
    __shared__ uint32_t bh[4096];                  // interpolation bins (16 KiB)
    __shared__ uint32_t cs[1024];
    __shared__ unsigned long long lbuf[4096];      // bin members / fallback hist (32 KiB)
    __shared__ float sbf[CC];
    __shared__ uint32_t scnt;
    __shared__ int sh_d, sh_done, sh_b;
    __shared__ uint32_t sh_r;
    __shared__ unsigned long long sh_thr;
    int row = blockIdx.x, tid = threadIdx.x;
    int K = *kptr;
    uint32_t cnt = counters[row], c_hi = chi[row];
    uint32_t Thi = thi[row], Tlo = tlo[row];
    long long Ell = (long long)K - (long long)c_hi;
    unsigned long long* cp = cand + (size_t)row * cap;
    const float* xr = x + (size_t)row * NPR;
    float* orow = out + (size_t)row * NPR;

    bool ok = (Ell >= 0) && (Ell <= (long long)cnt) && ((int)cnt <= cap) && (Thi > Tlo);
    if (ok) {
        if (Ell == 0) return;
        uint32_t E = (uint32_t)Ell;
        uint32_t R = Thi - Tlo;                    // >= 1
        unsigned long long scale = (4096ULL << 32) / R;   // bin = rel*scale >> 32 < 4096
        for (int i = tid; i < 4096; i += 1024) bh[i] = 0;
        __syncthreads();
        for (uint32_t s = tid; s < cnt; s += 1024) {
            uint32_t key = (uint32_t)(cp[s] >> 32);
            uint32_t rel = key - Tlo - 1;          // candidates: Tlo < key <= Thi
            uint32_t bin = (uint32_t)(((unsigned long long)rel * scale) >> 32);
            if (bin > 4095u) bin = 4095u;
            atomicAdd(&bh[bin], 1u);
        }
        __syncthreads();
        int hi = 4095 - 4 * tid;                   // 4 bins per thread, descending
        uint32_t s4 = bh[hi] + bh[hi-1] + bh[hi-2] + bh[hi-3];
        cs[tid] = s4;
        __syncthreads();
        for (int off = 1; off < 1024; off <<= 1) {
            uint32_t v = (tid >= off) ? cs[tid - off] : 0u;
            __syncthreads();
            cs[tid] += v;
            __syncthreads();
        }
        uint32_t incl = cs[tid], excl = incl - s4;
        if (excl < E && incl >= E) {
            uint32_t cum = excl;
            for (int j = 0; j < 4; j++) {
                int b = hi - j;
                uint32_t h = bh[b];
                if (cum + h >= E) { sh_b = b; sh_r = E - cum; break; }
                cum += h;
            }
        }
        __syncthreads();
        int bstar = sh_b;
        uint32_t r = sh_r;                         // rank within bin, 1-indexed
        uint32_t mm = bh[bstar];
        unsigned long long thr;
        if (mm <= 4096u) {
            if (tid == 0) scnt = 0;
            __syncthreads();
            for (uint32_t s = tid; s < cnt; s += 1024) {
                unsigned long long v = cp[s];
                uint32_t key = (uint32_t)(v >> 32);
                uint32_t rel = key - Tlo - 1;
                uint32_t bin = (uint32_t)(((unsigned long long)rel * scale) >> 32);
                if (bin > 4095u) bin = 4095u;
                if ((int)bin == bstar) lbuf[atomicAdd(&scnt, 1u)] = v;
            }
            __syncthreads();
            // pairwise rank (values distinct); inner reads broadcast (same addr)
            for (uint32_t i = tid; i < mm; i += 1024) {
                unsigned long long vi = lbuf[i];
                uint32_t above = 0;
                for (uint32_t j2 = 0; j2 < mm; j2++) above += (lbuf[j2] > vi);
                if (above == r - 1) sh_thr = vi;
            }
            __syncthreads();
            thr = sh_thr;
        } else {                                   // wild skew (rare): raw radix
            thr = select64(cp, cnt, E, bh, cs, lbuf, &scnt, &sh_d, &sh_done);
        }
        for (uint32_t s = tid; s < cnt; s += 1024) {
            unsigned long long v = cp[s];
            if (v >= thr) { uint32_t j = ~(uint32_t)v; orow[j] = xr[j]; }
        }
        return;
    }

    // ------- fallback: exact full-row recompute (bracket miss, prob ~1e-4) ----
    uint32_t* lh = (uint32_t*)lbuf;                // 8192 bins (32 KiB)
    if (tid < CC) sbf[tid] = boostf(dc, tid, K);
    for (int i = tid; i < 8192; i += 1024) lh[i] = 0;
    __syncthreads();
    const float4* xp = (const float4*)xr;
    for (int t = tid; t < NF4; t += 1024) {
        float4 v = xp[t];
        float f = sbf[t / F4CH];
        atomicAdd(&lh[tokey(v.x * f) >> 19], 1u);
        atomicAdd(&lh[tokey(v.y * f) >> 19], 1u);
        atomicAdd(&lh[tokey(v.z * f) >> 19], 1u);
        atomicAdd(&lh[tokey(v.w * f) >> 19], 1u);
    }
    __syncthreads();
    {
        int hi = 8191 - 8 * tid;
        uint32_t s = 0;
        for (int j = 0; j < 8; j++) s += lh[hi - j];
        cs[tid] = s;
        __syncthreads();
        for (int off = 1; off < 1024; off <<= 1) {
            uint32_t v = (tid >= off) ? cs[tid - off] : 0u;
            __syncthreads();
            cs[tid] += v;
            __syncthreads();
        }
        uint32_t incl = cs[tid], excl = incl - s;
        if (excl < (uint32_t)K && incl >= (uint32_t)K) {
            uint32_t cum = excl;
            for (int j = 0; j < 8; j++) {
                int b = hi - j;
                uint32_t h = lh[b];
                if (cum + h >= (uint32_t)K) { sh_b = b; sh_r = (uint32_t)K - cum; break; }
                cum += h;
            }
        }
    }
    __syncthreads();
    int bstar = sh_b;
    uint32_t E2 = sh_r;
    if (tid == 0) scnt = 0;
    __syncthreads();
    for (int t = tid; t < NF4; t += 1024) {        // rewrite out + compact boundary bin
        float4 v = xp[t];
        float f = sbf[t / F4CH];
        vf4 o;
        float* vi = (float*)&v;
        #pragma unroll
        for (int q = 0; q < 4; q++) {
            float xv = vi[q];
            uint32_t key = tokey(xv * f);
            int bin = (int)(key >> 19);
            o[q] = (bin > bstar) ? xv : 0.0f;
            if (bin == bstar) {
                uint32_t j = (uint32_t)(4 * t + q);
                unsigned long long packed = ((unsigned long long)key << 32) | (uint32_t)(~j);
                uint32_t p = atomicAdd(&scnt, 1u);
                if ((int)p < cap) cp[p] = packed;
            }
        }
        ((vf4*)orow)[t] = o;
    }
    __syncthreads();
    uint32_t cnt2 = scnt;
    if ((int)cnt2 > cap) cnt2 = (uint32_t)cap;
    unsigned long long thr = select64(cp, cnt2, E2, bh, cs, lbuf, &scnt, &sh_d, &sh_done);
    for (uint32_t s = tid; s < cnt2; s += 1024) {
        unsigned long long v = cp[s];
        if (v >= thr) { uint32_t j = ~(uint32_t)v; orow[j] = xr[j]; }
    }
}

extern "C" void kernel_launch(void* const* d_in, const int* in_sizes, int n_in,
                              void* d_out, int out_size, void* d_ws, size_t ws_size,
                              hipStream_t stream) {
    const float* x  = (const float*)d_in[0];
    const float* dc = (const float*)d_in[1];
    const int* kptr = (const int*)d_in[2];
    float* out = (float*)d_out;

    char* ws = (char*)d_ws;
    uint32_t* thi      = (uint32_t*)(ws + THI_OFF);
    uint32_t* tlo      = (uint32_t*)(ws + TLO_OFF);
    uint32_t* chi      = (uint32_t*)(ws + CHI_OFF);
    uint32_t* counters = (uint32_t*)(ws + CNT_OFF);
    unsigned long long* cand = (unsigned long long*)(ws + CAND_OFF);

    size_t cap_sz = (ws_size > CAND_OFF) ? (ws_size - CAND_OFF) / ((size_t)BB * 8) : 0;
    if (cap_sz > 65536) cap_sz = 65536;
    int cap = (int)cap_sz;

    (void)hipMemsetAsync(ws, 0, 4096, stream);     // zero thresholds/counters only
    k_sample<<<BB, 1024, 0, stream>>>(x, dc, kptr, thi, tlo);
    k_stream<<<BB * 16, 256, 0, stream>>>(x, dc, kptr, thi, tlo, out, cand, counters, chi, cap);
    k_final<<<BB, 1024, 0, stream>>>(x, dc, kptr, thi, tlo, out, cand, counters, chi, cap);
}

// Round 7
// 267.696 us; speedup vs baseline: 1.2951x; 1.0352x over previous
//
#include <hip/hip_runtime.h>
#include <stdint.h>

// Problem shape (fixed by setup_inputs)
#define BB 64
#define CC 128
#define HW 3136
#define NPR (CC * HW)        // 401408 per row
#define NF4 (NPR / 4)        // 100352
#define F4CH (HW / 4)        // 784 float4 per channel
#define MARGIN 128           // sample-rank margin (~4.7 sigma; exact fallback guards)

typedef float vf4 __attribute__((ext_vector_type(4)));

// ws layout: [0,256) Thi u32[64] | [256,512) Tlo | [512,768) chi | [768,1024) counters
//            [4096, ...) cand u64[64][cap]  (packed key<<32 | ~idx)
#define THI_OFF 0
#define TLO_OFF 256
#define CHI_OFF 512
#define CNT_OFF 768
#define CAND_OFF 4096

__device__ __forceinline__ uint32_t tokey(float b) {
    uint32_t u = __float_as_uint(b);
    return u ^ (uint32_t)(((int32_t)u >> 31) | 0x80000000);
}
__device__ __forceinline__ float fromkey(uint32_t k) {
    uint32_t u = (k & 0x80000000u) ? (k ^ 0x80000000u) : ~k;
    return __uint_as_float(u);
}

__device__ __forceinline__ float boostf(const float* dc, int c, int K) {
    float td = (float)((double)K / (double)NPR);   // jnp.float32(k/n)
    float d = td - dc[c];
    return (float)exp((double)d);
}

// m-th largest among 8 in-register keys per thread (1024-thr block), 3 passes
// -> 24-bit truncated threshold (low 8 bits zero). Truncation shifts counts by
// ~4 full-array ranks, absorbed by MARGIN; exact fallback guards regardless.
// Per-wave privatized histograms break same-address LDS atomic serialization.
__device__ uint32_t select32(const uint32_t* kreg, uint32_t m,
                             uint32_t* whist /*16*256*/, uint32_t* sufs, int* sh_d) {
    int tid = threadIdx.x;
    int wid = tid >> 6;
    uint32_t prefix = 0, mask = 0, remaining = m;
    for (int shift = 24; shift >= 8; shift -= 8) {
        for (int i = tid; i < 16 * 256; i += 1024) whist[i] = 0;
        __syncthreads();
        #pragma unroll
        for (int i = 0; i < 8; i++) {
            uint32_t v = kreg[i];
            if ((v & mask) == prefix)
                atomicAdd(&whist[(wid << 8) + ((v >> shift) & 255u)], 1u);
        }
        __syncthreads();
        if (tid < 256) {
            uint32_t s = 0;
            for (int w = 0; w < 16; w++) s += whist[(w << 8) + tid];
            sufs[tid] = s;
        }
        __syncthreads();
        for (int off = 1; off < 256; off <<= 1) {  // suffix sums (descending)
            uint32_t add = 0;
            if (tid < 256 && tid + off < 256) add = sufs[tid + off];
            __syncthreads();
            if (tid < 256) sufs[tid] += add;
            __syncthreads();
        }
        if (tid < 256) {
            uint32_t sd = sufs[tid], sn = (tid < 255) ? sufs[tid + 1] : 0u;
            if (sd >= remaining && sn < remaining) *sh_d = tid;
        }
        __syncthreads();
        int d = *sh_d;
        uint32_t cumG = (d < 255) ? sufs[d + 1] : 0u;
        prefix |= ((uint32_t)d << shift);
        mask |= (0xFFu << shift);
        remaining -= cumG;
        __syncthreads();
    }
    return prefix;
}

// exact E-th largest u64 among cnt candidates (rare path / fallback only)
__device__ unsigned long long select64(const unsigned long long* cp, uint32_t cnt,
                                       uint32_t E, uint32_t* hh, uint32_t* sufs,
                                       unsigned long long* lbuf, uint32_t* scnt,
                                       int* sh_d, int* sh_done) {
    int tid = threadIdx.x, nt = blockDim.x;
    unsigned long long prefix = 0ull, mask = 0ull, thr = 0ull;
    uint32_t remaining = E, csize = cnt;
    bool compacted = false;
    if (tid == 0) *sh_done = 0;
    __syncthreads();
    for (int shift = 56; shift >= 0; shift -= 8) {
        if (tid < 256) hh[tid] = 0;
        __syncthreads();
        if (!compacted) {
            for (uint32_t s = tid; s < cnt; s += nt) {
                unsigned long long v = cp[s];
                if ((v & mask) == prefix)
                    atomicAdd(&hh[(uint32_t)(v >> shift) & 255u], 1u);
            }
        } else {
            for (uint32_t s = tid; s < csize; s += nt)
                atomicAdd(&hh[(uint32_t)(lbuf[s] >> shift) & 255u], 1u);
        }
        __syncthreads();
        if (tid < 256) sufs[tid] = hh[tid];
        __syncthreads();
        for (int off = 1; off < 256; off <<= 1) {
            uint32_t add = 0;
            if (tid < 256 && tid + off < 256) add = sufs[tid + off];
            __syncthreads();
            if (tid < 256) sufs[tid] += add;
            __syncthreads();
        }
        if (tid < 256) {
            uint32_t sd = sufs[tid], sn = (tid < 255) ? sufs[tid + 1] : 0u;
            if (sd >= remaining && sn < remaining) *sh_d = tid;
        }
        __syncthreads();
        int d = *sh_d;
        uint32_t cumG = (d < 255) ? sufs[d + 1] : 0u;
        uint32_t binC = sufs[d] - cumG;
        unsigned long long npref = prefix | ((unsigned long long)(uint32_t)d << shift);
        bool done_ = (sufs[d] == remaining);
        if (done_) { thr = npref; if (tid == 0) *sh_done = 1; }
        remaining -= cumG;
        __syncthreads();
        if (!*sh_done && binC <= 4096u && shift > 0) {
            if (tid == 0) *scnt = 0;
            unsigned long long keep[8]; int nk = 0;
            if (compacted) {
                for (uint32_t s = tid; s < csize; s += nt) {
                    unsigned long long v = lbuf[s];
                    if (((uint32_t)(v >> shift) & 255u) == (uint32_t)d && nk < 8)
                        keep[nk++] = v;
                }
            }
            __syncthreads();
            if (!compacted) {
                for (uint32_t s = tid; s < cnt; s += nt) {
                    unsigned long long v = cp[s];
                    if ((v & mask) == prefix &&
                        ((uint32_t)(v >> shift) & 255u) == (uint32_t)d)
                        lbuf[atomicAdd(scnt, 1u)] = v;
                }
            } else if (nk > 0) {
                uint32_t p = atomicAdd(scnt, (uint32_t)nk);
                for (int i = 0; i < nk; i++) lbuf[p + i] = keep[i];
            }
            __syncthreads();
            csize = binC;
            compacted = true;
        }
        prefix = npref;
        mask |= (0xFFull << shift);
        if (*sh_done) break;
    }
    __syncthreads();
    if (!*sh_done) thr = prefix;
    return thr;
}

// ---- kernel 1: 2 blocks/row; sample 8192/row (coalesced chunks), one
//      threshold per block via 3-pass radix select ---------------------------
__global__ __launch_bounds__(1024) void k_sample(const float* __restrict__ x,
                                                 const float* __restrict__ dc,
                                                 const int* __restrict__ kptr,
                                                 uint32_t* __restrict__ thi,
                                                 uint32_t* __restrict__ tlo) {
    __shared__ float sbf[CC];
    __shared__ uint32_t whist[16 * 256];           // 16 KiB
    __shared__ uint32_t sufs[256];
    __shared__ int sh_d;
    int row = blockIdx.x >> 1, which = blockIdx.x & 1;
    int tid = threadIdx.x;
    int K = *kptr;
    if (tid < CC) sbf[tid] = boostf(dc, tid, K);
    __syncthreads();
    const float4* xp = (const float4*)(x + (size_t)row * NPR);
    uint32_t kreg[8];
    #pragma unroll
    for (int h = 0; h < 2; h++) {
        int s = tid + h * 1024;                    // sample idx [0, 2048)
        int c = s >> 4, i = s & 15;                // 16 contiguous f4 per channel
        float4 v = xp[c * F4CH + i];               // coalesced 256B chunks
        float f = sbf[c];
        kreg[4*h+0] = tokey(v.x * f); kreg[4*h+1] = tokey(v.y * f);
        kreg[4*h+2] = tokey(v.z * f); kreg[4*h+3] = tokey(v.w * f);
    }
    int S = 8192;
    int m_mid = (int)(((long long)K * S) / NPR);
    int m = which ? (m_mid + MARGIN) : (m_mid - MARGIN);
    if (m < 1) m = 1;
    if (m > S) m = S;
    uint32_t t1 = select32(kreg, (uint32_t)m, whist, sufs, &sh_d);
    if (tid == 0) { if (which) tlo[row] = t1; else thi[row] = t1; }
}

// wave-aggregated LDS append of a candidate
__device__ __forceinline__ void push_cand(bool isc, unsigned long long packed,
                                          uint32_t* lcnt, unsigned long long* lbuf,
                                          uint32_t* counters, unsigned long long* cand,
                                          int row, int cap) {
    unsigned long long ball = __ballot(isc);
    uint32_t tot = (uint32_t)__popcll(ball);
    if (tot == 0) return;
    uint32_t lo = (uint32_t)ball, hi = (uint32_t)(ball >> 32);
    uint32_t lanepre = __builtin_amdgcn_mbcnt_hi(hi, __builtin_amdgcn_mbcnt_lo(lo, 0));
    int leader = __ffsll((unsigned long long)ball) - 1;
    uint32_t base = 0;
    if (isc && lanepre == 0) base = atomicAdd(lcnt, tot);
    base = __shfl(base, leader, 64);
    if (isc) {
        uint32_t pos = base + lanepre;
        if (pos < 4096u) lbuf[pos] = packed;
        else {
            uint32_t gp = atomicAdd(&counters[row], 1u);
            if ((int)gp < cap) cand[(size_t)row * cap + gp] = packed;
        }
    }
}

// ---- kernel 2: stream out=x*(b>Bhi), count sure-winners, compact bracket ----
// SW-pipelined: next loads issue BEFORE current stores -> in-order vmcnt
// retirement lets NT stores float behind; 2 loads/thread in flight.
__global__ __launch_bounds__(256) void k_stream(const float* __restrict__ x,
                                                const float* __restrict__ dc,
                                                const int* __restrict__ kptr,
                                                const uint32_t* __restrict__ thi,
                                                const uint32_t* __restrict__ tlo,
                                                float* __restrict__ out,
                                                unsigned long long* __restrict__ cand,
                                                uint32_t* __restrict__ counters,
                                                uint32_t* __restrict__ chi,
                                                int cap) {
    int row = blockIdx.x >> 4;                     // 64 rows x 16 groups of 8 channels
    int c0 = (blockIdx.x & 15) * 8;
    float Bhi = fromkey(thi[row]);
    float Blo = fromkey(tlo[row]);

    __shared__ float sbf[8];
    __shared__ uint32_t lcnt, gbase;
    __shared__ unsigned long long lbuf[4096];      // 32 KiB
    __shared__ uint32_t red[256];
    if (threadIdx.x == 0) lcnt = 0;
    if (threadIdx.x < 8) sbf[threadIdx.x] = boostf(dc, c0 + threadIdx.x, *kptr);
    __syncthreads();

    size_t base = (size_t)row * NPR + (size_t)c0 * HW;
    const float4* xp = (const float4*)(x + base);
    vf4* op = (vf4*)(out + base);
    int jbase = c0 * HW;
    int tid = threadIdx.x;
    uint32_t myhi = 0;

    auto proc = [&](int t, float4 v) {
        float f = sbf[t / F4CH];
        vf4 o;
        float* vi = (float*)&v;
        #pragma unroll
        for (int q = 0; q < 4; q++) {
            float xv = vi[q];
            float bv = xv * f;
            bool win = bv > Bhi;
            myhi += win;
            o[q] = win ? xv : 0.0f;
            bool isc = (bv > Blo) && !win;
            uint32_t j = (uint32_t)(jbase + 4 * t + q);
            unsigned long long packed =
                ((unsigned long long)tokey(bv) << 32) | (uint32_t)(~j);
            push_cand(isc, packed, &lcnt, lbuf, counters, cand, row, cap);
        }
        __builtin_nontemporal_store(o, &op[t]);
    };

    // 6272 f4 per block = 12 pair-iterations of 512 + tail 128
    float4 a = xp[tid];
    float4 b = xp[tid + 256];
    for (int p = 0; p < 12; ++p) {
        int t0 = p * 512 + tid;
        float4 a2, b2;
        if (p < 11) { a2 = xp[t0 + 512]; b2 = xp[t0 + 768]; }
        else if (tid < 128) { a2 = xp[6144 + tid]; }
        proc(t0, a);
        proc(t0 + 256, b);
        a = a2; b = b2;
    }
    if (tid < 128) proc(6144 + tid, a);

    __syncthreads();
    uint32_t m = lcnt < 4096u ? lcnt : 4096u;
    if (threadIdx.x == 0) gbase = atomicAdd(&counters[row], m);
    __syncthreads();
    for (uint32_t i = threadIdx.x; i < m; i += 256) {
        uint32_t pos = gbase + i;
        if ((int)pos < cap) cand[(size_t)row * cap + pos] = lbuf[i];
    }
    red[threadIdx.x] = myhi;
    __syncthreads();
    for (int off = 128; off > 0; off >>= 1) {
        if ((int)threadIdx.x < off) red[threadIdx.x] += red[threadIdx.x + off];
        __syncthreads();
    }
    if (threadIdx.x == 0) atomicAdd(&chi[row], red[0]);
}

// ---- kernel 3: interpolation-select exact E-th among candidates + scatter ----
__global__ __launch_bounds__(1024) void k_final(const float* __restrict__ x,
                                                const float* __restrict__ dc,
                                                const int* __restrict__ kptr,
                                                const uint32_t* __restrict__ thi,
                                                const uint32_t* __restrict__ tlo,
                                                float* __restrict__ out,
                                                unsigned long long* __restrict__ cand,
                                                const uint32_t* __restrict__ counters,
                                                const uint32_t* __restrict__ chi,
                                                int cap) {
    __shared__ uint32_t bh[4096];                  // interpolation bins (16 KiB)
    __shared__ uint32_t cs[1024];
    __shared__ unsigned long long lbuf[4096];      // bin members / fallback hist (32 KiB)
    __shared__ float sbf[CC];
    __shared__ uint32_t scnt;
    __shared__ int sh_d, sh_done, sh_b;
    __shared__ uint32_t sh_r;
    __shared__ unsigned long long sh_thr;
    int row = blockIdx.x, tid = threadIdx.x;
    int K = *kptr;
    uint32_t cnt = counters[row], c_hi = chi[row];
    uint32_t Thi = thi[row], Tlo = tlo[row];
    long long Ell = (long long)K - (long long)c_hi;
    unsigned long long* cp = cand + (size_t)row * cap;
    const float* xr = x + (size_t)row * NPR;
    float* orow = out + (size_t)row * NPR;

    bool ok = (Ell >= 0) && (Ell <= (long long)cnt) && ((int)cnt <= cap) && (Thi > Tlo);
    if (ok) {
        if (Ell == 0) return;
        uint32_t E = (uint32_t)Ell;
        uint32_t R = Thi - Tlo;                    // >= 1
        unsigned long long scale = (4096ULL << 32) / R;   // bin = rel*scale >> 32 < 4096
        for (int i = tid; i < 4096; i += 1024) bh[i] = 0;
        __syncthreads();
        for (uint32_t s = tid; s < cnt; s += 1024) {
            uint32_t key = (uint32_t)(cp[s] >> 32);
            uint32_t rel = key - Tlo - 1;          // candidates: Tlo < key <= Thi
            uint32_t bin = (uint32_t)(((unsigned long long)rel * scale) >> 32);
            if (bin > 4095u) bin = 4095u;
            atomicAdd(&bh[bin], 1u);
        }
        __syncthreads();
        int hi = 4095 - 4 * tid;                   // 4 bins per thread, descending
        uint32_t s4 = bh[hi] + bh[hi-1] + bh[hi-2] + bh[hi-3];
        cs[tid] = s4;
        __syncthreads();
        for (int off = 1; off < 1024; off <<= 1) {
            uint32_t v = (tid >= off) ? cs[tid - off] : 0u;
            __syncthreads();
            cs[tid] += v;
            __syncthreads();
        }
        uint32_t incl = cs[tid], excl = incl - s4;
        if (excl < E && incl >= E) {
            uint32_t cum = excl;
            for (int j = 0; j < 4; j++) {
                int b = hi - j;
                uint32_t h = bh[b];
                if (cum + h >= E) { sh_b = b; sh_r = E - cum; break; }
                cum += h;
            }
        }
        __syncthreads();
        int bstar = sh_b;
        uint32_t r = sh_r;                         // rank within bin, 1-indexed
        uint32_t mm = bh[bstar];
        unsigned long long thr;
        if (mm <= 4096u) {
            if (tid == 0) scnt = 0;
            __syncthreads();
            for (uint32_t s = tid; s < cnt; s += 1024) {
                unsigned long long v = cp[s];
                uint32_t key = (uint32_t)(v >> 32);
                uint32_t rel = key - Tlo - 1;
                uint32_t bin = (uint32_t)(((unsigned long long)rel * scale) >> 32);
                if (bin > 4095u) bin = 4095u;
                if ((int)bin == bstar) lbuf[atomicAdd(&scnt, 1u)] = v;
            }
            __syncthreads();
            // pairwise rank (values distinct); inner reads broadcast (same addr)
            for (uint32_t i = tid; i < mm; i += 1024) {
                unsigned long long vi = lbuf[i];
                uint32_t above = 0;
                for (uint32_t j2 = 0; j2 < mm; j2++) above += (lbuf[j2] > vi);
                if (above == r - 1) sh_thr = vi;
            }
            __syncthreads();
            thr = sh_thr;
        } else {                                   // wild skew (rare): raw radix
            thr = select64(cp, cnt, E, bh, cs, lbuf, &scnt, &sh_d, &sh_done);
        }
        for (uint32_t s = tid; s < cnt; s += 1024) {
            unsigned long long v = cp[s];
            if (v >= thr) { uint32_t j = ~(uint32_t)v; orow[j] = xr[j]; }
        }
        return;
    }

    // ------- fallback: exact full-row recompute (bracket miss, prob ~0) -------
    uint32_t* lh = (uint32_t*)lbuf;                // 8192 bins (32 KiB)
    if (tid < CC) sbf[tid] = boostf(dc, tid, K);
    for (int i = tid; i < 8192; i += 1024) lh[i] = 0;
    __syncthreads();
    const float4* xp = (const float4*)xr;
    for (int t = tid; t < NF4; t += 1024) {
        float4 v = xp[t];
        float f = sbf[t / F4CH];
        atomicAdd(&lh[tokey(v.x * f) >> 19], 1u);
        atomicAdd(&lh[tokey(v.y * f) >> 19], 1u);
        atomicAdd(&lh[tokey(v.z * f) >> 19], 1u);
        atomicAdd(&lh[tokey(v.w * f) >> 19], 1u);
    }
    __syncthreads();
    {
        int hi = 8191 - 8 * tid;
        uint32_t s = 0;
        for (int j = 0; j < 8; j++) s += lh[hi - j];
        cs[tid] = s;
        __syncthreads();
        for (int off = 1; off < 1024; off <<= 1) {
            uint32_t v = (tid >= off) ? cs[tid - off] : 0u;
            __syncthreads();
            cs[tid] += v;
            __syncthreads();
        }
        uint32_t incl = cs[tid], excl = incl - s;
        if (excl < (uint32_t)K && incl >= (uint32_t)K) {
            uint32_t cum = excl;
            for (int j = 0; j < 8; j++) {
                int b = hi - j;
                uint32_t h = lh[b];
                if (cum + h >= (uint32_t)K) { sh_b = b; sh_r = (uint32_t)K - cum; break; }
                cum += h;
            }
        }
    }
    __syncthreads();
    int bstar = sh_b;
    uint32_t E2 = sh_r;
    if (tid == 0) scnt = 0;
    __syncthreads();
    for (int t = tid; t < NF4; t += 1024) {        // rewrite out + compact boundary bin
        float4 v = xp[t];
        float f = sbf[t / F4CH];
        vf4 o;
        float* vi = (float*)&v;
        #pragma unroll
        for (int q = 0; q < 4; q++) {
            float xv = vi[q];
            uint32_t key = tokey(xv * f);
            int bin = (int)(key >> 19);
            o[q] = (bin > bstar) ? xv : 0.0f;
            if (bin == bstar) {
                uint32_t j = (uint32_t)(4 * t + q);
                unsigned long long packed = ((unsigned long long)key << 32) | (uint32_t)(~j);
                uint32_t p = atomicAdd(&scnt, 1u);
                if ((int)p < cap) cp[p] = packed;
            }
        }
        ((vf4*)orow)[t] = o;
    }
    __syncthreads();
    uint32_t cnt2 = scnt;
    if ((int)cnt2 > cap) cnt2 = (uint32_t)cap;
    unsigned long long thr = select64(cp, cnt2, E2, bh, cs, lbuf, &scnt, &sh_d, &sh_done);
    for (uint32_t s = tid; s < cnt2; s += 1024) {
        unsigned long long v = cp[s];
        if (v >= thr) { uint32_t j = ~(uint32_t)v; orow[j] = xr[j]; }
    }
}

extern "C" void kernel_launch(void* const* d_in, const int* in_sizes, int n_in,
                              void* d_out, int out_size, void* d_ws, size_t ws_size,
                              hipStream_t stream) {
    const float* x  = (const float*)d_in[0];
    const float* dc = (const float*)d_in[1];
    const int* kptr = (const int*)d_in[2];
    float* out = (float*)d_out;

    char* ws = (char*)d_ws;
    uint32_t* thi      = (uint32_t*)(ws + THI_OFF);
    uint32_t* tlo      = (uint32_t*)(ws + TLO_OFF);
    uint32_t* chi      = (uint32_t*)(ws + CHI_OFF);
    uint32_t* counters = (uint32_t*)(ws + CNT_OFF);
    unsigned long long* cand = (unsigned long long*)(ws + CAND_OFF);

    size_t cap_sz = (ws_size > CAND_OFF) ? (ws_size - CAND_OFF) / ((size_t)BB * 8) : 0;
    if (cap_sz > 65536) cap_sz = 65536;
    int cap = (int)cap_sz;

    (void)hipMemsetAsync(ws + CHI_OFF, 0, 512, stream);   // zero chi + counters only
    k_sample<<<BB * 2, 1024, 0, stream>>>(x, dc, kptr, thi, tlo);
    k_stream<<<BB * 16, 256, 0, stream>>>(x, dc, kptr, thi, tlo, out, cand, counters, chi, cap);
    k_final<<<BB, 1024, 0, stream>>>(x, dc, kptr, thi, tlo, out, cand, counters, chi, cap);
}